// Round 6
// baseline (403.893 us; speedup 1.0000x reference)
//
#include <hip/hip_runtime.h>

// ---- problem constants ----
#define TT   512
#define BI   12
#define HH   50
#define BB   8     // batch per block
#define BTOT 2048
#define LOG2E 1.4426950408889634f

// R15 = R12 base (R14's partner-read REVERTED: same-addr b128 pairs are
// NOT broadcast -> 65x conflicts) restructured into a HALF-STEP LAYER
// STAGGER. Evidence: 25% idle survives VALU cuts (R11/R12), vmcnt drain
// removal (R13), LDS perturbation (R14: +195cy/step conflicts -> only
// +56cy step; LDS 70% hidden). Model: 16-wave phase lockstep -> the
// read+MFMA window (ds latency + dep chain) has NO VALU work block-wide.
// Fix: 2 phases/step, layers antiphase (both layers' inputs are already
// published at the step boundary):
//   Phase A: L0 read+MFMA (VALU-idle) || L1 act+write h1[t-2] (VALU-heavy)
//   Phase B: L0 act+write h0[t]      || L1 read+MFMA (pre-act h1[t-1])
// Deps (each write->read separated by >=1 barrier, verified):
//   L0 MFMA(t) reads B0s[P_t]: h0[t-1],x[t] written phase B t-1. OK
//   L1 MFMA(t) reads B0s[P_t] (h0[t-1]) + B1s[P_t] (h1[t-2], written
//     phase A this step, BarA separates). OK  L1 act writes B1s[P_t].
//   WAR: buffer parity flips per step; rewrite is >=2 barriers after
//     last read. x[t+1] stored phase B t into B0s[1-P] (x rows disjoint
//     from h0 rows). Raw lgkmcnt-barrier (R13: correct + neutral) so the
//     x global load floats across barriers; issued phase A, stored next
//     phase B (~1 step in flight).
// Pipeline: step t produces h0[t], h1[t-2]; steps 0..513; h1[511] written
// phase A of t=513 into B1s[1]; 2 extra drain steps vs R12 (exact).
// Carried: trans fusion (5 exp2 + 2 rcp), scales folded into f16 weights,
// fzero C-operand, unified h0 buffer, LDS 8KB, 2-ahead xhold prefetch.
// Layout (verified R5-R14): row r = u*4+gate -> lane's f4 acc holds all 4
// gates of one (unit,batch); cell update in-register; B frags [k>>3][n][k&7].

typedef _Float16 half8 __attribute__((ext_vector_type(8)));
typedef float    f4    __attribute__((ext_vector_type(4)));

__device__ __forceinline__ float sigm_(float v) {
    return __builtin_amdgcn_rcpf(1.f + __builtin_amdgcn_exp2f(v * (-LOG2E)));
}
// lanes with (lane&15)<8 keep a0; lanes with (lane&15)>=8 take a1 from
// lane^8 (DPP row_ror:8 = 0x128, banks 2,3 -> bank_mask 0xC). One VALU op.
__device__ __forceinline__ float dppmerge_(float a0, float a1) {
    int r = __builtin_amdgcn_update_dpp(__builtin_bit_cast(int, a0),
                                        __builtin_bit_cast(int, a1),
                                        0x128, 0xF, 0xC, false);
    return __builtin_bit_cast(float, r);
}

__launch_bounds__(1024)
__global__ void lstm2_kernel(const float* __restrict__ x,
                             const float* __restrict__ w_ih0, const float* __restrict__ w_hh0,
                             const float* __restrict__ b_ih0, const float* __restrict__ b_hh0,
                             const float* __restrict__ w_ih1, const float* __restrict__ w_hh1,
                             const float* __restrict__ b_ih1, const float* __restrict__ b_hh1,
                             const float* __restrict__ w_out, const float* __restrict__ b_out,
                             float* __restrict__ out)
{
    const int tid   = threadIdx.x;
    const int wv    = tid >> 6;          // 0..15
    const int lane  = tid & 63;
    const int layer = wv >> 3;           // 0 or 1
    const int w8    = wv & 7;
    const int b0    = blockIdx.x * BB;
    // 13 M-tiles per layer over 8 waves: waves 0-4 take 2, waves 5-7 take 1.
    const int t0     = (w8 < 5) ? 2 * w8 : (5 + w8);
    const int ntiles = (w8 < 5) ? 2 : 1;

    // K-space: B0s rows = [h0: 0-49 | x: 50-61 | bias(=1): 62 | pad: 63]
    //          B1s rows = [h1: 0-49 | unused: 50-61 | bias(=1): 62 | pad: 63]
    __shared__ __align__(16) _Float16 B0s[2][64 * 16];
    __shared__ __align__(16) _Float16 B1s[2][64 * 16];

    // ---- step-invariant A fragments (weights, fragment layout, pre-scaled) ----
    const int m = lane & 15;
    const int q = lane >> 4;
    half8 af[2][4];
    #pragma unroll
    for (int s = 0; s < 2; s++) {
        #pragma unroll
        for (int kb = 0; kb < 4; kb++) {
            #pragma unroll
            for (int j = 0; j < 8; j++) {
                float v = 0.f;
                if (s < ntiles && (layer == 1 || kb < 2)) {
                    const int T  = t0 + s;
                    const int u  = T * 4 + (m >> 2);
                    const int g  = m & 3;
                    const int kg = kb * 32 + q * 8 + j;
                    if (u < HH) {
                        const int r = g * HH + u;
                        if (layer == 0) {
                            if      (kg < 50)  v = w_hh0[r * HH + kg];
                            else if (kg < 62)  v = w_ih0[r * BI + (kg - 50)];
                            else if (kg == 62) v = b_ih0[r] + b_hh0[r];
                        } else {
                            if      (kg < 50)               v = w_ih1[r * HH + kg];
                            else if (kg >= 64 && kg < 114)  v = w_hh1[r * HH + (kg - 64)];
                            else if (kg == 126)             v = b_ih1[r] + b_hh1[r];
                        }
                        // fold activation input scale into the weight
                        v *= (g == 2) ? (2.f * LOG2E) : (-LOG2E);
                    }
                }
                af[s][kb][j] = (_Float16)v;
            }
        }
    }

    // ---- init LDS ----
    for (int i = tid; i < 2 * 64 * 16; i += 1024) {
        (&B0s[0][0])[i] = (_Float16)0.f;
        (&B1s[0][0])[i] = (_Float16)0.f;
    }
    __syncthreads();
    if (tid < 16) {                       // bias (ones) row 62, both parities
        B0s[0][7 * 128 + tid * 8 + 6] = (_Float16)1.f;
        B0s[1][7 * 128 + tid * 8 + 6] = (_Float16)1.f;
        B1s[0][7 * 128 + tid * 8 + 6] = (_Float16)1.f;
        B1s[1][7 * 128 + tid * 8 + 6] = (_Float16)1.f;
    }
    const int xb = tid / 12, xi = tid - xb * 12;           // loop-invariant
    const int xrow = 50 + xi;
    const int xoff = (xrow >> 3) * 128 + xb * 8 + (xrow & 7);
    const size_t xbase = ((size_t)(b0 + xb) * TT) * BI + xi;
    if (tid < 96)                          // x[0] -> parity 0
        B0s[0][xoff] = (_Float16)x[xbase];
    __syncthreads();

    // ---- merged update role: lane owns (u_m, bcol) ----
    const int n16  = lane & 15;
    const int slot = n16 >> 3;            // 0: own acc0; 1: partner's acc1
    const int bcol = n16 & 7;
    const int u_m  = (t0 + slot) * 4 + q;
    const bool wvalid = (u_m < HH) && (slot == 0 || ntiles == 2);
    float cm = 0.f;                        // cell state for (u_m, bcol)

    // ---- per-parity pointers (constant-indexed -> folded at compile time) ----
    const _Float16* rd0[2] = { &B0s[0][0] + lane * 8, &B0s[1][0] + lane * 8 };
    const _Float16* rd1[2] = { &B1s[0][0] + lane * 8, &B1s[1][0] + lane * 8 };
    const int offA = (u_m >> 3) * 128 + bcol * 8 + (u_m & 7);   // h row = u_m
    _Float16* wAp[2] = { (layer ? &B1s[0][0] : &B0s[0][0]) + offA,
                         (layer ? &B1s[1][0] : &B0s[1][0]) + offA };
    _Float16* xdp[2] = { &B0s[0][0] + xoff, &B0s[1][0] + xoff };

    const f4 fzero = {0.f, 0.f, 0.f, 0.f};

    // ---- persistent pipeline registers ----
    f4 acc0v = fzero, acc1v = fzero;      // L0: MFMA result, phase A -> B
    f4 am1   = fzero;                     // L1: merged pre-act, phase B -> next A
    float xnewP = 0.f;                    // x load, phase A -> phase B

    // x stream, 2-step-ahead: xhold carries x[t+1] across a full step.
    const float* xq = x + xbase + BI;     // points at x[1]
    float xhold = 0.f;
    if (tid < 96) xhold = *xq;            // preload x[1]
    xq += BI;                             // points at x[2]

// Raw barrier: LDS drain only (R13-verified). x global load floats across.
#define BARX()                                                                \
    asm volatile("s_waitcnt lgkmcnt(0)" ::: "memory");                        \
    __builtin_amdgcn_s_barrier();                                             \
    asm volatile("" ::: "memory");

// Fused activation + cell update + h write (exact algebra, R12-verified):
//   eI..eO = 2^am (pre-scaled args); cm' = [cm*dI*dG+(eG-1)*dF]*rcp(dF*dI*dG)
//   h = (eC-1)*rcp(dO*(1+eC)), eC = 2^min(2log2e*cm', 60)
#define DOACT(AM, WPTR)                                                       \
  {                                                                           \
    const float eI = __builtin_amdgcn_exp2f((AM)[0]);                         \
    const float eF = __builtin_amdgcn_exp2f((AM)[1]);                         \
    const float eG = __builtin_amdgcn_exp2f((AM)[2]);                         \
    const float eO = __builtin_amdgcn_exp2f((AM)[3]);                         \
    const float dI = 1.f + eI, dF = 1.f + eF;                                 \
    const float dG = 1.f + eG, dO = 1.f + eO;                                 \
    const float pIG = dI * dG;                                                \
    const float num = __builtin_fmaf(cm, pIG, (eG - 1.f) * dF);               \
    cm = num * __builtin_amdgcn_rcpf(dF * pIG);                               \
    const float uu = fminf(cm * (2.f * LOG2E), 60.f);                         \
    const float eC = __builtin_amdgcn_exp2f(uu);                              \
    const float h_ = (eC - 1.f) * __builtin_amdgcn_rcpf(dO * (1.f + eC));     \
    if (wvalid) *(WPTR) = (_Float16)h_;                                       \
  }

// Phase A of step t (parity P=t&1): L0 read+MFMA; L1 act+write h1[t-2]->B1s[P].
#define PHASEA(P, A0, A1, DOLD)                                               \
  {                                                                           \
    if ((DOLD) && tid < 96) xnewP = *xq;                                      \
    if (layer == 0) {                                                         \
      if (A0) {                                                               \
        const half8 bf0 = *(const half8*)(rd0[P]);                            \
        const half8 bf1 = *(const half8*)(rd0[P] + 512);                      \
        acc0v = __builtin_amdgcn_mfma_f32_16x16x32_f16(af[0][0], bf0, fzero, 0, 0, 0); \
        acc0v = __builtin_amdgcn_mfma_f32_16x16x32_f16(af[0][1], bf1, acc0v, 0, 0, 0); \
        if (ntiles > 1) {                                                     \
          acc1v = __builtin_amdgcn_mfma_f32_16x16x32_f16(af[1][0], bf0, fzero, 0, 0, 0); \
          acc1v = __builtin_amdgcn_mfma_f32_16x16x32_f16(af[1][1], bf1, acc1v, 0, 0, 0); \
        }                                                                     \
      }                                                                       \
    } else {                                                                  \
      if (A1) DOACT(am1, wAp[P])                                              \
    }                                                                         \
    BARX()                                                                    \
  }

// Phase B of step t: L0 act+write h0[t]->B0s[1-P]; L1 read(B0s[P],B1s[P])
// +MFMA -> am1 (pre-act h1[t-1]). x[t+1] stored to B0s[1-P].
#define PHASEB(P, B0, B1, DOST, DOLD)                                         \
  {                                                                           \
    if ((DOST) && tid < 96) *xdp[1 - (P)] = (_Float16)xhold;                  \
    if (layer == 0) {                                                         \
      if (B0) {                                                               \
        f4 am;                                                                \
        _Pragma("unroll")                                                     \
        for (int i = 0; i < 4; i++) am[i] = dppmerge_(acc0v[i], acc1v[i]);    \
        DOACT(am, wAp[1 - (P)])                                               \
      }                                                                       \
    } else {                                                                  \
      if (B1) {                                                               \
        const half8 bf0 = *(const half8*)(rd0[P]);                            \
        const half8 bf1 = *(const half8*)(rd0[P] + 512);                      \
        const half8 bf2 = *(const half8*)(rd1[P]);                            \
        const half8 bf3 = *(const half8*)(rd1[P] + 512);                      \
        f4 a0  = __builtin_amdgcn_mfma_f32_16x16x32_f16(af[0][0], bf0, fzero, 0, 0, 0); \
        f4 a0b = __builtin_amdgcn_mfma_f32_16x16x32_f16(af[0][1], bf1, fzero, 0, 0, 0); \
        a0  = __builtin_amdgcn_mfma_f32_16x16x32_f16(af[0][2], bf2, a0,  0, 0, 0);      \
        a0b = __builtin_amdgcn_mfma_f32_16x16x32_f16(af[0][3], bf3, a0b, 0, 0, 0);      \
        f4 acc0 = a0 + a0b, acc1 = fzero;                                     \
        if (ntiles > 1) {                                                     \
          f4 a1  = __builtin_amdgcn_mfma_f32_16x16x32_f16(af[1][0], bf0, fzero, 0, 0, 0); \
          f4 a1b = __builtin_amdgcn_mfma_f32_16x16x32_f16(af[1][1], bf1, fzero, 0, 0, 0); \
          a1  = __builtin_amdgcn_mfma_f32_16x16x32_f16(af[1][2], bf2, a1,  0, 0, 0);      \
          a1b = __builtin_amdgcn_mfma_f32_16x16x32_f16(af[1][3], bf3, a1b, 0, 0, 0);      \
          acc1 = a1 + a1b;                                                    \
        }                                                                     \
        _Pragma("unroll")                                                     \
        for (int i = 0; i < 4; i++) am1[i] = dppmerge_(acc0[i], acc1[i]);     \
      }                                                                       \
    }                                                                         \
    if (DOLD) { xhold = xnewP; xq += BI; }                                    \
    BARX()                                                                    \
  }

    // t=0: L0 only; load x[2], store x[1]
    PHASEA(0, 1, 0, 1) PHASEB(0, 1, 0, 1, 1)
    // t=1: L1's first MFMA (h1[0] pre-act; h1[-1]=0 from zero-init B1s[1])
    PHASEA(1, 1, 0, 1) PHASEB(1, 1, 1, 1, 1)
    #pragma unroll 1
    for (int it = 0; it < 254; ++it) {    // t = 2 .. 509
        PHASEA(0, 1, 1, 1) PHASEB(0, 1, 1, 1, 1)
        PHASEA(1, 1, 1, 1) PHASEB(1, 1, 1, 1, 1)
    }
    PHASEA(0, 1, 1, 0) PHASEB(0, 1, 1, 1, 0)   // t=510: store x[511], no load
    PHASEA(1, 1, 1, 0) PHASEB(1, 1, 1, 0, 0)   // t=511: last L0 step
    PHASEA(0, 0, 1, 0) PHASEB(0, 0, 1, 0, 0)   // t=512: L1 drain (MFMA h1[511])
    PHASEA(1, 0, 1, 0)                          // t=513: write h1[511]->B1s[1]
#undef PHASEA
#undef PHASEB
#undef DOACT
#undef BARX

    __syncthreads();

    // ---- epilogue: sigmoid(h1[TT-1] . w_out + b_out); h1[511] in B1s[1] ----
    if (tid < BB) {
        float s = b_out[0];
        #pragma unroll
        for (int u = 0; u < HH; u++) {
            s += w_out[u] * (float)B1s[1][(u >> 3) * 128 + tid * 8 + (u & 7)];
        }
        out[b0 + tid] = sigm_(s);
    }
}

extern "C" void kernel_launch(void* const* d_in, const int* in_sizes, int n_in,
                              void* d_out, int out_size, void* d_ws, size_t ws_size,
                              hipStream_t stream) {
    const float* x     = (const float*)d_in[0];
    const float* w_ih0 = (const float*)d_in[1];
    const float* w_hh0 = (const float*)d_in[2];
    const float* b_ih0 = (const float*)d_in[3];
    const float* b_hh0 = (const float*)d_in[4];
    const float* w_ih1 = (const float*)d_in[5];
    const float* w_hh1 = (const float*)d_in[6];
    const float* b_ih1 = (const float*)d_in[7];
    const float* b_hh1 = (const float*)d_in[8];
    const float* w_out = (const float*)d_in[9];
    const float* b_out = (const float*)d_in[10];
    float* out = (float*)d_out;

    dim3 grid(BTOT / BB);   // 256 blocks -> 1 per CU
    dim3 block(1024);       // 16 waves: 8 layer-0 + 8 layer-1
    lstm2_kernel<<<grid, block, 0, stream>>>(x, w_ih0, w_hh0, b_ih0, b_hh0,
                                             w_ih1, w_hh1, b_ih1, b_hh1,
                                             w_out, b_out, out);
}

// Round 7
// 355.251 us; speedup vs baseline: 1.1369x; 1.1369x over previous
//
#include <hip/hip_runtime.h>

// ---- problem constants ----
#define TT   512
#define BI   12
#define HH   50
#define BB   8     // batch per block
#define BTOT 2048
#define LOG2E 1.4426950408889634f

// R16 = R12 (324 us, best: setprio on L1 + __syncthreads + trans fusion)
// with issue-work shed from critical waves (R15 stagger REVERTED: +6%,
// barrier ~85-100cy each; structure is issue-bound: VALU 723 + MFMA 320
// = 75% of the 1390cy step, act is ON the recurrence path):
//  - x-duty moved from waves 0-1 (2-tile L0 + x = near-critical) to the
//    PERMANENTLY INVALID slot-1 lanes of the three L0 1-tile waves
//    (wv 5-7): 3 x 32 = 96 x-slots exactly. Critical waves lose ~8 VALU
//    + 1 VMEM + 1 ds_write per step; the work lands on lanes that were
//    executing masked garbage.
//  - L1 MFMA back to 4-deep chains (R10's split reverted): -8 v_add_f32
//    per L1 wave. Issue-bound regime favors fewer instructions over
//    shorter dep chains (chain latency hides under cross-wave issue).
// Carried from R12: trans fusion (5 exp2 + 2 rcp, common-denominator
// cell update, exp2-arg clamp 60), scales folded into f16 weights, fzero
// C-operand, unified h0 buffer (B0s=[h0 0-49|x 50-61|bias 62],
// B1s=[h1 0-49|bias 62], LDS 8KB), 2-ahead xhold prefetch, s_setprio(1)
// on L1 waves.
// Layout (verified R5-R15): row r = u*4+gate -> lane's f4 acc holds all 4
// gates of one (unit,batch); cell update in-register. B fragments in LDS
// order [k>>3][n][k&7]; ping-pong parities; one barrier/step; layers
// software-pipelined by one step (exact): step t: l0->h0[t], l1->h1[t-1].

typedef _Float16 half8 __attribute__((ext_vector_type(8)));
typedef float    f4    __attribute__((ext_vector_type(4)));

__device__ __forceinline__ float sigm_(float v) {
    return __builtin_amdgcn_rcpf(1.f + __builtin_amdgcn_exp2f(v * (-LOG2E)));
}
// lanes with (lane&15)<8 keep a0; lanes with (lane&15)>=8 take a1 from
// lane^8 (DPP row_ror:8 = 0x128, banks 2,3 -> bank_mask 0xC). One VALU op.
__device__ __forceinline__ float dppmerge_(float a0, float a1) {
    int r = __builtin_amdgcn_update_dpp(__builtin_bit_cast(int, a0),
                                        __builtin_bit_cast(int, a1),
                                        0x128, 0xF, 0xC, false);
    return __builtin_bit_cast(float, r);
}

__launch_bounds__(1024)
__global__ void lstm2_kernel(const float* __restrict__ x,
                             const float* __restrict__ w_ih0, const float* __restrict__ w_hh0,
                             const float* __restrict__ b_ih0, const float* __restrict__ b_hh0,
                             const float* __restrict__ w_ih1, const float* __restrict__ w_hh1,
                             const float* __restrict__ b_ih1, const float* __restrict__ b_hh1,
                             const float* __restrict__ w_out, const float* __restrict__ b_out,
                             float* __restrict__ out)
{
    const int tid   = threadIdx.x;
    const int wv    = tid >> 6;          // 0..15
    const int lane  = tid & 63;
    const int layer = wv >> 3;           // 0 or 1
    const int w8    = wv & 7;
    const int b0    = blockIdx.x * BB;
    // 13 M-tiles per layer over 8 waves: waves 0-4 take 2, waves 5-7 take 1.
    const int t0     = (w8 < 5) ? 2 * w8 : (5 + w8);
    const int ntiles = (w8 < 5) ? 2 : 1;

    // critical waves (layer 1: 4 K-block MFMA) win issue arbitration (R12)
    if (layer) __builtin_amdgcn_s_setprio(1);

    // K-space: B0s rows = [h0: 0-49 | x: 50-61 | bias(=1): 62 | pad: 63]
    //          B1s rows = [h1: 0-49 | unused: 50-61 | bias(=1): 62 | pad: 63]
    __shared__ __align__(16) _Float16 B0s[2][64 * 16];
    __shared__ __align__(16) _Float16 B1s[2][64 * 16];

    // ---- step-invariant A fragments (weights, fragment layout, pre-scaled) ----
    const int m = lane & 15;
    const int q = lane >> 4;
    half8 af[2][4];
    #pragma unroll
    for (int s = 0; s < 2; s++) {
        #pragma unroll
        for (int kb = 0; kb < 4; kb++) {
            #pragma unroll
            for (int j = 0; j < 8; j++) {
                float v = 0.f;
                if (s < ntiles && (layer == 1 || kb < 2)) {
                    const int T  = t0 + s;
                    const int u  = T * 4 + (m >> 2);
                    const int g  = m & 3;
                    const int kg = kb * 32 + q * 8 + j;
                    if (u < HH) {
                        const int r = g * HH + u;
                        if (layer == 0) {
                            if      (kg < 50)  v = w_hh0[r * HH + kg];
                            else if (kg < 62)  v = w_ih0[r * BI + (kg - 50)];
                            else if (kg == 62) v = b_ih0[r] + b_hh0[r];
                        } else {
                            if      (kg < 50)               v = w_ih1[r * HH + kg];
                            else if (kg >= 64 && kg < 114)  v = w_hh1[r * HH + (kg - 64)];
                            else if (kg == 126)             v = b_ih1[r] + b_hh1[r];
                        }
                        // fold activation input scale into the weight
                        v *= (g == 2) ? (2.f * LOG2E) : (-LOG2E);
                    }
                }
                af[s][kb][j] = (_Float16)v;
            }
        }
    }

    // ---- init LDS ----
    for (int i = tid; i < 2 * 64 * 16; i += 1024) {
        (&B0s[0][0])[i] = (_Float16)0.f;
        (&B1s[0][0])[i] = (_Float16)0.f;
    }
    __syncthreads();
    if (tid < 16) {                       // bias (ones) row 62, both parities
        B0s[0][7 * 128 + tid * 8 + 6] = (_Float16)1.f;
        B0s[1][7 * 128 + tid * 8 + 6] = (_Float16)1.f;
        B1s[0][7 * 128 + tid * 8 + 6] = (_Float16)1.f;
        B1s[1][7 * 128 + tid * 8 + 6] = (_Float16)1.f;
    }

    // ---- merged update role: lane owns (u_m, bcol) ----
    const int n16  = lane & 15;
    const int slot = n16 >> 3;            // 0: own acc0; 1: partner's acc1
    const int bcol = n16 & 7;
    const int u_m  = (t0 + slot) * 4 + q;
    const bool wvalid = (u_m < HH) && (slot == 0 || ntiles == 2);
    float cm = 0.f;                        // cell state for (u_m, bcol)

    // ---- x-duty on dead lanes: slot-1 lanes of L0 1-tile waves (wv 5-7) ----
    // Those lanes are permanently invalid for the update role (ntiles==1),
    // so x load/cvt/store costs them nothing useful; critical 2-tile waves
    // are freed of all x work. 3 waves x 32 lanes = 96 slots = BB*BI.
    const bool xact = (layer == 0) && (ntiles == 1) && (slot == 1);
    const int xidx  = (w8 - 5) * 32 + q * 8 + bcol;        // 0..95 on xact lanes
    const int xb    = xidx / 12, xi = xidx - xb * 12;
    const int xrow  = 50 + xi;
    const int xoff  = (xrow >> 3) * 128 + xb * 8 + (xrow & 7);
    const size_t xbase = ((size_t)(b0 + xb) * TT) * BI + xi;
    if (xact)                              // x[0] -> parity 0
        B0s[0][xoff] = (_Float16)x[xbase];
    __syncthreads();

    // ---- per-parity pointers (constant-indexed -> folded at compile time) ----
    const _Float16* rd0[2] = { &B0s[0][0] + lane * 8, &B0s[1][0] + lane * 8 };
    const _Float16* rd1[2] = { &B1s[0][0] + lane * 8, &B1s[1][0] + lane * 8 };
    const int offA = (u_m >> 3) * 128 + bcol * 8 + (u_m & 7);   // h row = u_m
    _Float16* wAp[2] = { (layer ? &B1s[0][0] : &B0s[0][0]) + offA,
                         (layer ? &B1s[1][0] : &B0s[1][0]) + offA };
    _Float16* xdp[2] = { &B0s[0][0] + xoff, &B0s[1][0] + xoff };

    const f4 fzero = {0.f, 0.f, 0.f, 0.f};

    // x stream, 2-step-ahead: xhold carries x[t+1] across a full step.
    const float* xq = x + xbase + BI;     // points at x[1]
    float xhold = 0.f;
    if (xact) xhold = *xq;                // preload x[1]
    xq += BI;                             // points at x[2]

// One timestep at compile-time parity P. DOL0/DOL1: layer activity
// (peel boundaries). DOST: store xhold (=x[t+1]) into parity 1-P.
// DOLD: issue load of x[t+2] (consumed next step).
// Act math (exact algebra; am[] = MFMA out = pre-scaled exp2 args):
//   eI=2^am0, eF=2^am1, eG=2^am2, eO=2^am3 (i,f,o args = -log2e*pre;
//   g arg = 2log2e*pre). fv=1/dF, iv*gv=(eG-1)/(dI*dG) ->
//   cm' = [cm*dI*dG + (eG-1)*dF] * rcp(dF*dI*dG)          (1 rcp)
//   h   = (eC-1) * rcp(dO*(1+eC)), eC=2^min(2log2e*cm',60) (1 rcp)
#define STEP(P, DOL0, DOL1, DOST, DOLD)                                       \
  {                                                                           \
    float xnew = 0.f;                                                         \
    if ((DOLD) && xact) xnew = *xq;                                           \
    if ((DOST) && xact) *xdp[1 - (P)] = (_Float16)xhold;                      \
    if ((layer == 0) ? (DOL0) : (DOL1)) {                                     \
      const half8 bf0 = *(const half8*)(rd0[P]);                              \
      const half8 bf1 = *(const half8*)(rd0[P] + 512);                        \
      f4 acc0, acc1 = fzero;                                                  \
      if (layer == 0) {                                                       \
        acc0 = __builtin_amdgcn_mfma_f32_16x16x32_f16(af[0][0], bf0, fzero, 0, 0, 0); \
        acc0 = __builtin_amdgcn_mfma_f32_16x16x32_f16(af[0][1], bf1, acc0, 0, 0, 0);  \
        if (ntiles > 1) {                                                     \
          acc1 = __builtin_amdgcn_mfma_f32_16x16x32_f16(af[1][0], bf0, fzero, 0, 0, 0); \
          acc1 = __builtin_amdgcn_mfma_f32_16x16x32_f16(af[1][1], bf1, acc1, 0, 0, 0);  \
        }                                                                     \
      } else {                                                                \
        const half8 bf2 = *(const half8*)(rd1[P]);                            \
        const half8 bf3 = *(const half8*)(rd1[P] + 512);                      \
        acc0 = __builtin_amdgcn_mfma_f32_16x16x32_f16(af[0][0], bf0, fzero, 0, 0, 0); \
        acc0 = __builtin_amdgcn_mfma_f32_16x16x32_f16(af[0][1], bf1, acc0, 0, 0, 0);  \
        acc0 = __builtin_amdgcn_mfma_f32_16x16x32_f16(af[0][2], bf2, acc0, 0, 0, 0);  \
        acc0 = __builtin_amdgcn_mfma_f32_16x16x32_f16(af[0][3], bf3, acc0, 0, 0, 0);  \
        if (ntiles > 1) {                                                     \
          acc1 = __builtin_amdgcn_mfma_f32_16x16x32_f16(af[1][0], bf0, fzero, 0, 0, 0); \
          acc1 = __builtin_amdgcn_mfma_f32_16x16x32_f16(af[1][1], bf1, acc1, 0, 0, 0);  \
          acc1 = __builtin_amdgcn_mfma_f32_16x16x32_f16(af[1][2], bf2, acc1, 0, 0, 0);  \
          acc1 = __builtin_amdgcn_mfma_f32_16x16x32_f16(af[1][3], bf3, acc1, 0, 0, 0);  \
        }                                                                     \
      }                                                                       \
      f4 am;                                                                  \
      _Pragma("unroll")                                                       \
      for (int i = 0; i < 4; i++) am[i] = dppmerge_(acc0[i], acc1[i]);        \
      const float eI = __builtin_amdgcn_exp2f(am[0]);                         \
      const float eF = __builtin_amdgcn_exp2f(am[1]);                         \
      const float eG = __builtin_amdgcn_exp2f(am[2]);                         \
      const float eO = __builtin_amdgcn_exp2f(am[3]);                         \
      const float dI = 1.f + eI, dF = 1.f + eF;                               \
      const float dG = 1.f + eG, dO = 1.f + eO;                               \
      const float pIG = dI * dG;                                              \
      const float num = __builtin_fmaf(cm, pIG, (eG - 1.f) * dF);             \
      cm = num * __builtin_amdgcn_rcpf(dF * pIG);                             \
      const float uu = fminf(cm * (2.f * LOG2E), 60.f);                       \
      const float eC = __builtin_amdgcn_exp2f(uu);                            \
      const float h  = (eC - 1.f) * __builtin_amdgcn_rcpf(dO * (1.f + eC));   \
      if (wvalid) *wAp[1 - (P)] = (_Float16)h;                                \
    }                                                                         \
    if (DOLD) { xhold = xnew; xq += BI; }                                     \
    __syncthreads();                                                          \
  }

    STEP(0, 1, 0, 1, 1)                   // t = 0   (l0 only; store x[1], load x[2])
    STEP(1, 1, 1, 1, 1)                   // t = 1
    #pragma unroll 1
    for (int it = 0; it < 254; ++it) {    // t = 2 .. 509
        STEP(0, 1, 1, 1, 1)
        STEP(1, 1, 1, 1, 1)
    }
    STEP(0, 1, 1, 1, 0)                   // t = 510 (store x[511], no more loads)
    STEP(1, 1, 1, 0, 0)                   // t = 511
    STEP(0, 0, 1, 0, 0)                   // t = 512 (l1 only)
#undef STEP

    // ---- epilogue: sigmoid(h1[TT-1] . w_out + b_out); h1[TT-1] in parity 1 ----
    if (tid < BB) {
        float s = b_out[0];
        #pragma unroll
        for (int u = 0; u < HH; u++) {
            s += w_out[u] * (float)B1s[1][(u >> 3) * 128 + tid * 8 + (u & 7)];
        }
        out[b0 + tid] = sigm_(s);
    }
}

extern "C" void kernel_launch(void* const* d_in, const int* in_sizes, int n_in,
                              void* d_out, int out_size, void* d_ws, size_t ws_size,
                              hipStream_t stream) {
    const float* x     = (const float*)d_in[0];
    const float* w_ih0 = (const float*)d_in[1];
    const float* w_hh0 = (const float*)d_in[2];
    const float* b_ih0 = (const float*)d_in[3];
    const float* b_hh0 = (const float*)d_in[4];
    const float* w_ih1 = (const float*)d_in[5];
    const float* w_hh1 = (const float*)d_in[6];
    const float* b_ih1 = (const float*)d_in[7];
    const float* b_hh1 = (const float*)d_in[8];
    const float* w_out = (const float*)d_in[9];
    const float* b_out = (const float*)d_in[10];
    float* out = (float*)d_out;

    dim3 grid(BTOT / BB);   // 256 blocks -> 1 per CU
    dim3 block(1024);       // 16 waves: 8 layer-0 + 8 layer-1
    lstm2_kernel<<<grid, block, 0, stream>>>(x, w_ih0, w_hh0, b_ih0, b_hh0,
                                             w_ih1, w_hh1, b_ih1, b_hh1,
                                             w_out, b_out, out);
}

// Round 8
// 349.984 us; speedup vs baseline: 1.1540x; 1.0150x over previous
//
#include <hip/hip_runtime.h>

// ---- problem constants ----
#define TT   512
#define BI   12
#define HH   50
#define BB   8     // batch per block
#define BTOT 2048
#define LOG2E 1.4426950408889634f

// R17 = R16 (313 us; VALUBusy 53, MfmaUtil 24, ~23% lockstep idle)
// restructured: ONE WAVE = ONE M-TILE = BOTH LAYERS.
//  - wave w (0..12) owns tile w for L0 AND L1: reads bf0/bf1 = B0s[P]
//    (h0(t-1)+x(t)+bias; SHARED by both layers' MFMAs -- L1's A already
//    zeroes cols 50-63) and bf2/bf3 = B1s[P] (h1(t-2)+bias);
//    acc0 = L0 2-chain, acc1 = L1 4-chain.
//  - the R5-verified dppmerge now merges LAYERS instead of tiles: slot0
//    lanes (n16<8) keep acc0 -> own L0 cell (u_m,bcol); slot1 lanes take
//    acc1 from lane^8 -> own L1 cell. ONE act bundle per wave serves both
//    layers; writes go to B0s (slot0) / B1s (slot1) at row u_m.
//  - lane utilization: 100% on waves 0-11 (vs 50% on 6 of 16 waves);
//    act bundles 16->13; MFMAs unchanged (78/CU-step); ONE barrier/step.
//    Every wave now has both MFMA and VALU work each step -> the
//    post-barrier read+MFMA window overlaps other waves' act (the 23%
//    idle R15's 2-barrier stagger failed to recover).
//  - parity logic IDENTICAL to R16 (reads [P], writes [1-P]; h0(t) in
//    B0s[1-P], h1(t-1) in B1s[1-P]); peel flags identical; per-lane
//    actp = slot ? DOL1 : DOL0 replaces the per-wave layer gate (folds
//    away in the main loop; in peel steps predicates cm update + write).
//  - x-duty on 3 light waves (wv 13-15, lanes 0-31 = 96 slots), as R16's
//    dead-lane scheme; setprio(1) on compute waves.
// Carried: trans fusion (5 exp2 + 2 rcp, clamp 60), scales folded into
// f16 weights, fzero C-operand, unified h0 buffer (B0s=[h0 0-49|x 50-61|
// bias 62], B1s=[h1 0-49|bias 62]), LDS 8KB, 2-ahead xhold prefetch.

typedef _Float16 half8 __attribute__((ext_vector_type(8)));
typedef float    f4    __attribute__((ext_vector_type(4)));

__device__ __forceinline__ float sigm_(float v) {
    return __builtin_amdgcn_rcpf(1.f + __builtin_amdgcn_exp2f(v * (-LOG2E)));
}
// lanes with (lane&15)<8 keep a0; lanes with (lane&15)>=8 take a1 from
// lane^8 (DPP row_ror:8 = 0x128, banks 2,3 -> bank_mask 0xC). One VALU op.
__device__ __forceinline__ float dppmerge_(float a0, float a1) {
    int r = __builtin_amdgcn_update_dpp(__builtin_bit_cast(int, a0),
                                        __builtin_bit_cast(int, a1),
                                        0x128, 0xF, 0xC, false);
    return __builtin_bit_cast(float, r);
}

__launch_bounds__(1024)
__global__ void lstm2_kernel(const float* __restrict__ x,
                             const float* __restrict__ w_ih0, const float* __restrict__ w_hh0,
                             const float* __restrict__ b_ih0, const float* __restrict__ b_hh0,
                             const float* __restrict__ w_ih1, const float* __restrict__ w_hh1,
                             const float* __restrict__ b_ih1, const float* __restrict__ b_hh1,
                             const float* __restrict__ w_out, const float* __restrict__ b_out,
                             float* __restrict__ out)
{
    const int tid   = threadIdx.x;
    const int wv    = tid >> 6;          // 0..15
    const int lane  = tid & 63;
    const int b0    = blockIdx.x * BB;

    const int m    = lane & 15;
    const int q    = lane >> 4;          // 0..3
    const int slot = m >> 3;             // 0: L0 role, 1: L1 role
    const int bcol = m & 7;
    const int T    = wv;                 // M-tile (compute waves only)
    const bool comp = (wv < 13);
    const int u_m  = T * 4 + q;          // unit owned by this lane
    const bool wvalid = comp && (u_m < HH);

    if (comp) __builtin_amdgcn_s_setprio(1);

    // K-space: B0s rows = [h0: 0-49 | x: 50-61 | bias(=1): 62 | pad: 63]
    //          B1s rows = [h1: 0-49 | unused: 50-61 | bias(=1): 62 | pad: 63]
    __shared__ __align__(16) _Float16 B0s[2][64 * 16];
    __shared__ __align__(16) _Float16 B1s[2][64 * 16];

    // ---- step-invariant A fragments (pre-scaled), tile T, both layers ----
    const int uA = T * 4 + (m >> 2);     // A-fragment row unit
    const int gA = m & 3;                // gate
    half8 af0[2], af1[4];
    #pragma unroll
    for (int kb = 0; kb < 2; kb++) {
        #pragma unroll
        for (int j = 0; j < 8; j++) {
            float v = 0.f;
            if (comp && uA < HH) {
                const int r  = gA * HH + uA;
                const int kg = kb * 32 + q * 8 + j;
                if      (kg < 50)  v = w_hh0[r * HH + kg];
                else if (kg < 62)  v = w_ih0[r * BI + (kg - 50)];
                else if (kg == 62) v = b_ih0[r] + b_hh0[r];
                v *= (gA == 2) ? (2.f * LOG2E) : (-LOG2E);
            }
            af0[kb][j] = (_Float16)v;
        }
    }
    #pragma unroll
    for (int kb = 0; kb < 4; kb++) {
        #pragma unroll
        for (int j = 0; j < 8; j++) {
            float v = 0.f;
            if (comp && uA < HH) {
                const int r  = gA * HH + uA;
                const int kg = kb * 32 + q * 8 + j;
                if      (kg < 50)               v = w_ih1[r * HH + kg];
                else if (kg >= 64 && kg < 114)  v = w_hh1[r * HH + (kg - 64)];
                else if (kg == 126)             v = b_ih1[r] + b_hh1[r];
                v *= (gA == 2) ? (2.f * LOG2E) : (-LOG2E);
            }
            af1[kb][j] = (_Float16)v;
        }
    }

    // ---- init LDS ----
    for (int i = tid; i < 2 * 64 * 16; i += 1024) {
        (&B0s[0][0])[i] = (_Float16)0.f;
        (&B1s[0][0])[i] = (_Float16)0.f;
    }
    __syncthreads();
    if (tid < 16) {                       // bias (ones) row 62, both parities
        B0s[0][7 * 128 + tid * 8 + 6] = (_Float16)1.f;
        B0s[1][7 * 128 + tid * 8 + 6] = (_Float16)1.f;
        B1s[0][7 * 128 + tid * 8 + 6] = (_Float16)1.f;
        B1s[1][7 * 128 + tid * 8 + 6] = (_Float16)1.f;
    }

    // ---- x-duty: waves 13-15, lanes 0-31 -> 96 slots = BB*BI ----
    const bool xact = (wv >= 13) && (lane < 32);
    const int xidx  = (wv - 13) * 32 + lane;               // 0..95 on xact
    const int xb    = xidx / 12, xi = xidx - xb * 12;
    const int xrow  = 50 + xi;
    const int xoff  = (xrow >> 3) * 128 + xb * 8 + (xrow & 7);
    const size_t xbase = ((size_t)(b0 + xb) * TT) * BI + xi;
    if (xact)                              // x[0] -> parity 0
        B0s[0][xoff] = (_Float16)x[xbase];
    __syncthreads();

    // ---- per-parity pointers (loop-invariant) ----
    const _Float16* rd0[2] = { &B0s[0][0] + lane * 8, &B0s[1][0] + lane * 8 };
    const _Float16* rd1[2] = { &B1s[0][0] + lane * 8, &B1s[1][0] + lane * 8 };
    const int offA = (u_m >> 3) * 128 + bcol * 8 + (u_m & 7);   // h row = u_m
    _Float16* wAp[2] = { (slot ? &B1s[0][0] : &B0s[0][0]) + offA,
                         (slot ? &B1s[1][0] : &B0s[1][0]) + offA };
    _Float16* xdp[2] = { &B0s[0][0] + xoff, &B0s[1][0] + xoff };

    const f4 fzero = {0.f, 0.f, 0.f, 0.f};
    float cm = 0.f;                        // cell state for (slot-layer, u_m, bcol)

    // x stream, 2-step-ahead: xhold carries x[t+1] across a full step.
    const float* xq = x + xbase + BI;     // points at x[1]
    float xhold = 0.f;
    if (xact) xhold = *xq;                // preload x[1]
    xq += BI;                             // points at x[2]

// One timestep at compile-time parity P (identical flags/parity to R16).
// Per-lane activity: slot0 lanes live iff DOL0, slot1 iff DOL1 (folds to
// true in the main loop). MFMAs run unconditionally on compute waves
// (stale operands in peel steps are discarded by the predicate).
#define STEP(P, DOL0, DOL1, DOST, DOLD)                                       \
  {                                                                           \
    float xnew = 0.f;                                                         \
    if ((DOLD) && xact) xnew = *xq;                                           \
    if ((DOST) && xact) *xdp[1 - (P)] = (_Float16)xhold;                      \
    if (comp) {                                                               \
      const half8 bf0 = *(const half8*)(rd0[P]);                              \
      const half8 bf1 = *(const half8*)(rd0[P] + 512);                        \
      const half8 bf2 = *(const half8*)(rd1[P]);                              \
      const half8 bf3 = *(const half8*)(rd1[P] + 512);                        \
      f4 acc0, acc1;                                                          \
      acc0 = __builtin_amdgcn_mfma_f32_16x16x32_f16(af0[0], bf0, fzero, 0, 0, 0); \
      acc0 = __builtin_amdgcn_mfma_f32_16x16x32_f16(af0[1], bf1, acc0, 0, 0, 0);  \
      acc1 = __builtin_amdgcn_mfma_f32_16x16x32_f16(af1[0], bf0, fzero, 0, 0, 0); \
      acc1 = __builtin_amdgcn_mfma_f32_16x16x32_f16(af1[1], bf1, acc1, 0, 0, 0);  \
      acc1 = __builtin_amdgcn_mfma_f32_16x16x32_f16(af1[2], bf2, acc1, 0, 0, 0);  \
      acc1 = __builtin_amdgcn_mfma_f32_16x16x32_f16(af1[3], bf3, acc1, 0, 0, 0);  \
      f4 am;                                                                  \
      _Pragma("unroll")                                                       \
      for (int i = 0; i < 4; i++) am[i] = dppmerge_(acc0[i], acc1[i]);        \
      const float eI = __builtin_amdgcn_exp2f(am[0]);                         \
      const float eF = __builtin_amdgcn_exp2f(am[1]);                         \
      const float eG = __builtin_amdgcn_exp2f(am[2]);                         \
      const float eO = __builtin_amdgcn_exp2f(am[3]);                         \
      const float dI = 1.f + eI, dF = 1.f + eF;                               \
      const float dG = 1.f + eG, dO = 1.f + eO;                               \
      const float pIG = dI * dG;                                              \
      const float num = __builtin_fmaf(cm, pIG, (eG - 1.f) * dF);             \
      const float cmn = num * __builtin_amdgcn_rcpf(dF * pIG);                \
      const float uu  = fminf(cmn * (2.f * LOG2E), 60.f);                     \
      const float eC  = __builtin_amdgcn_exp2f(uu);                           \
      const float h   = (eC - 1.f) * __builtin_amdgcn_rcpf(dO * (1.f + eC));  \
      const bool actp = slot ? (bool)(DOL1) : (bool)(DOL0);                   \
      if (actp) cm = cmn;                                                     \
      if (actp && wvalid) *wAp[1 - (P)] = (_Float16)h;                        \
    }                                                                         \
    if (DOLD) { xhold = xnew; xq += BI; }                                     \
    __syncthreads();                                                          \
  }

    STEP(0, 1, 0, 1, 1)                   // t = 0   (l0 only; store x[1], load x[2])
    STEP(1, 1, 1, 1, 1)                   // t = 1
    #pragma unroll 1
    for (int it = 0; it < 254; ++it) {    // t = 2 .. 509
        STEP(0, 1, 1, 1, 1)
        STEP(1, 1, 1, 1, 1)
    }
    STEP(0, 1, 1, 1, 0)                   // t = 510 (store x[511], no more loads)
    STEP(1, 1, 1, 0, 0)                   // t = 511
    STEP(0, 0, 1, 0, 0)                   // t = 512 (l1 drain: h1[511] -> B1s[1])
#undef STEP

    // ---- epilogue: sigmoid(h1[TT-1] . w_out + b_out); h1[511] in B1s[1] ----
    if (tid < BB) {
        float s = b_out[0];
        #pragma unroll
        for (int u = 0; u < HH; u++) {
            s += w_out[u] * (float)B1s[1][(u >> 3) * 128 + tid * 8 + (u & 7)];
        }
        out[b0 + tid] = sigm_(s);
    }
}

extern "C" void kernel_launch(void* const* d_in, const int* in_sizes, int n_in,
                              void* d_out, int out_size, void* d_ws, size_t ws_size,
                              hipStream_t stream) {
    const float* x     = (const float*)d_in[0];
    const float* w_ih0 = (const float*)d_in[1];
    const float* w_hh0 = (const float*)d_in[2];
    const float* b_ih0 = (const float*)d_in[3];
    const float* b_hh0 = (const float*)d_in[4];
    const float* w_ih1 = (const float*)d_in[5];
    const float* w_hh1 = (const float*)d_in[6];
    const float* b_ih1 = (const float*)d_in[7];
    const float* b_hh1 = (const float*)d_in[8];
    const float* w_out = (const float*)d_in[9];
    const float* b_out = (const float*)d_in[10];
    float* out = (float*)d_out;

    dim3 grid(BTOT / BB);   // 256 blocks -> 1 per CU
    dim3 block(1024);       // 13 merged-layer compute waves + 3 x-waves
    lstm2_kernel<<<grid, block, 0, stream>>>(x, w_ih0, w_hh0, b_ih0, b_hh0,
                                             w_ih1, w_hh1, b_ih1, b_hh1,
                                             w_out, b_out, out);
}